// Round 2
// baseline (75150.159 us; speedup 1.0000x reference)
//
#include <hip/hip_runtime.h>
#include <cstddef>

#define B_TOTAL  65536
#define OBS_LEN  20
#define PRED_LEN 30

__device__ __forceinline__ float sigm(float x) {
    return __builtin_amdgcn_rcpf(1.0f + __expf(-x));
}
__device__ __forceinline__ float tanh_f(float x) {
    return fmaf(2.0f, sigm(2.0f * x), -1.0f);
}

// One LSTM step for this thread's quarter of the hidden state.
// hf[64]   : full previous h (registers)
// cq[16]   : this quarter's c (registers, updated)
// e[32]    : embedded input (registers)
// writes new h quarter into h_lds row (stride 65)
template <int Q16>  // dummy template to guarantee inlining contexts are distinct
__device__ __forceinline__ void lstm_quarter(
    const float e[32], const float hf[64], float cq[16],
    const float* __restrict__ Wih, const float* __restrict__ Whh,
    const float* __restrict__ bias, int q, float* __restrict__ h_row)
{
#pragma unroll
    for (int jj = 0; jj < 16; ++jj) {
        const int j = q * 16 + jj;
        float ai = bias[j];
        float af = bias[64 + j];
        float ag = bias[128 + j];
        float ao = bias[192 + j];
#pragma unroll
        for (int k = 0; k < 32; ++k) {
            const float xv = e[k];
            ai = fmaf(Wih[j * 32 + k],         xv, ai);
            af = fmaf(Wih[(64 + j) * 32 + k],  xv, af);
            ag = fmaf(Wih[(128 + j) * 32 + k], xv, ag);
            ao = fmaf(Wih[(192 + j) * 32 + k], xv, ao);
        }
#pragma unroll
        for (int k = 0; k < 64; ++k) {
            const float hv = hf[k];
            ai = fmaf(Whh[j * 64 + k],         hv, ai);
            af = fmaf(Whh[(64 + j) * 64 + k],  hv, af);
            ag = fmaf(Whh[(128 + j) * 64 + k], hv, ag);
            ao = fmaf(Whh[(192 + j) * 64 + k], hv, ao);
        }
        const float iv = sigm(ai);
        const float fv = sigm(af);
        const float gv = tanh_f(ag);
        const float ov = sigm(ao);
        const float cn = fmaf(fv, cq[jj], iv * gv);
        cq[jj] = cn;
        h_row[j] = ov * tanh_f(cn);
    }
}

extern "C" __global__ void __launch_bounds__(256, 2)
traj_fused(const float* __restrict__ obs,
           const float* __restrict__ noise,
           const float* __restrict__ scene,
           const float* __restrict__ W_emb,  const float* __restrict__ b_emb,
           const float* __restrict__ Wih_e,  const float* __restrict__ Whh_e, const float* __restrict__ b_e,
           const float* __restrict__ W_h,    const float* __restrict__ b_h,
           const float* __restrict__ W_c,    const float* __restrict__ b_c,
           const float* __restrict__ Wih_d,  const float* __restrict__ Whh_d, const float* __restrict__ b_d,
           const float* __restrict__ W_out,  const float* __restrict__ b_out,
           float* __restrict__ out)
{
    // 256 threads = 4 waves. lane l = batch element (local), wave q = hidden quarter.
    __shared__ float h_lds[2][64][65];   // stride 65: bank=(l+k)%32 -> 2-way (free)

    const int l = threadIdx.x & 63;
    const int q = threadIdx.x >> 6;
    const int b = blockIdx.x * 64 + l;

    const float* ob = obs + (size_t)b * (OBS_LEN * 2);

    float hf[64];
    float cq[16];
#pragma unroll
    for (int k = 0; k < 64; ++k) hf[k] = 0.0f;
#pragma unroll
    for (int k = 0; k < 16; ++k) cq[k] = 0.0f;

    int buf = 0;

    // ---------------- encoder ----------------
#pragma unroll 1
    for (int t = 0; t < OBS_LEN; ++t) {
        const float x0 = ob[2 * t + 0];
        const float x1 = ob[2 * t + 1];
        float e[32];
#pragma unroll
        for (int k = 0; k < 32; ++k)
            e[k] = fmaxf(0.0f, fmaf(W_emb[2 * k], x0,
                                fmaf(W_emb[2 * k + 1], x1, b_emb[k])));

        lstm_quarter<0>(e, hf, cq, Wih_e, Whh_e, b_e, q, &h_lds[buf][l][0]);
        __syncthreads();
#pragma unroll
        for (int k = 0; k < 64; ++k) hf[k] = h_lds[buf][l][k];
        buf ^= 1;
    }

    // ---------------- cond -> decoder init state ----------------
    {
        float ah[16], ac[16];
#pragma unroll
        for (int jj = 0; jj < 16; ++jj) {
            ah[jj] = b_h[q * 16 + jj];
            ac[jj] = b_c[q * 16 + jj];
        }
#pragma unroll
        for (int k = 0; k < 64; ++k) {          // h_last part
            const float hv = hf[k];
#pragma unroll
            for (int jj = 0; jj < 16; ++jj) {
                ah[jj] = fmaf(W_h[(q * 16 + jj) * 144 + k], hv, ah[jj]);
                ac[jj] = fmaf(W_c[(q * 16 + jj) * 144 + k], hv, ac[jj]);
            }
        }
        const float* np_ = noise + (size_t)b * 16;
#pragma unroll 4
        for (int k = 0; k < 16; ++k) {          // noise part
            const float nv = np_[k];
#pragma unroll
            for (int jj = 0; jj < 16; ++jj) {
                ah[jj] = fmaf(W_h[(q * 16 + jj) * 144 + 64 + k], nv, ah[jj]);
                ac[jj] = fmaf(W_c[(q * 16 + jj) * 144 + 64 + k], nv, ac[jj]);
            }
        }
        const float* sp = scene + (size_t)b * 64;
#pragma unroll 4
        for (int k = 0; k < 64; ++k) {          // scene part
            const float sv = sp[k];
#pragma unroll
            for (int jj = 0; jj < 16; ++jj) {
                ah[jj] = fmaf(W_h[(q * 16 + jj) * 144 + 80 + k], sv, ah[jj]);
                ac[jj] = fmaf(W_c[(q * 16 + jj) * 144 + 80 + k], sv, ac[jj]);
            }
        }
        // h0/c0 are plain linear (no activation) per reference
#pragma unroll
        for (int jj = 0; jj < 16; ++jj) {
            h_lds[buf][l][q * 16 + jj] = ah[jj];
            cq[jj] = ac[jj];
        }
        __syncthreads();
#pragma unroll
        for (int k = 0; k < 64; ++k) hf[k] = h_lds[buf][l][k];
        buf ^= 1;
    }

    // ---------------- autoregressive decoder ----------------
    float x0 = ob[2 * (OBS_LEN - 1) + 0];
    float x1 = ob[2 * (OBS_LEN - 1) + 1];
    float* op = out + (size_t)b * (PRED_LEN * 2);

#pragma unroll 1
    for (int t = 0; t < PRED_LEN; ++t) {
        float e[32];
#pragma unroll
        for (int k = 0; k < 32; ++k)
            e[k] = fmaxf(0.0f, fmaf(W_emb[2 * k], x0,
                                fmaf(W_emb[2 * k + 1], x1, b_emb[k])));

        lstm_quarter<1>(e, hf, cq, Wih_d, Whh_d, b_d, q, &h_lds[buf][l][0]);
        __syncthreads();
#pragma unroll
        for (int k = 0; k < 64; ++k) hf[k] = h_lds[buf][l][k];
        buf ^= 1;

        // output head: all threads compute redundantly (keeps x0/x1 local, no sync)
        float y0 = b_out[0];
        float y1 = b_out[1];
#pragma unroll
        for (int j = 0; j < 64; ++j) {
            y0 = fmaf(W_out[j],      hf[j], y0);
            y1 = fmaf(W_out[64 + j], hf[j], y1);
        }
        if (q == 0) {                    // wave-uniform branch
            op[2 * t + 0] = y0;
            op[2 * t + 1] = y1;
        }
        x0 = y0;
        x1 = y1;
    }
}

extern "C" void kernel_launch(void* const* d_in, const int* in_sizes, int n_in,
                              void* d_out, int out_size, void* d_ws, size_t ws_size,
                              hipStream_t stream) {
    (void)in_sizes; (void)n_in; (void)d_ws; (void)ws_size; (void)out_size;
    const float* obs    = (const float*)d_in[0];
    const float* noise  = (const float*)d_in[1];
    const float* scene  = (const float*)d_in[2];
    const float* W_emb  = (const float*)d_in[3];
    const float* b_emb  = (const float*)d_in[4];
    const float* Wih_e  = (const float*)d_in[5];
    const float* Whh_e  = (const float*)d_in[6];
    const float* b_e    = (const float*)d_in[7];
    const float* W_h    = (const float*)d_in[8];
    const float* b_h    = (const float*)d_in[9];
    const float* W_c    = (const float*)d_in[10];
    const float* b_c    = (const float*)d_in[11];
    const float* Wih_d  = (const float*)d_in[12];
    const float* Whh_d  = (const float*)d_in[13];
    const float* b_d    = (const float*)d_in[14];
    const float* W_out  = (const float*)d_in[15];
    const float* b_out  = (const float*)d_in[16];
    float* out = (float*)d_out;

    dim3 grid(B_TOTAL / 64), block(256);
    hipLaunchKernelGGL(traj_fused, grid, block, 0, stream,
                       obs, noise, scene, W_emb, b_emb,
                       Wih_e, Whh_e, b_e, W_h, b_h, W_c, b_c,
                       Wih_d, Whh_d, b_d, W_out, b_out, out);
}

// Round 3
// 75144.678 us; speedup vs baseline: 1.0001x; 1.0001x over previous
//
#include <hip/hip_runtime.h>
#include <cstddef>

#define B_TOTAL  65536
#define OBS_LEN  20
#define PRED_LEN 30

__device__ __forceinline__ float sigm(float x) {
    return __builtin_amdgcn_rcpf(1.0f + __expf(-x));
}
__device__ __forceinline__ float tanh_f(float x) {
    return fmaf(2.0f, sigm(2.0f * x), -1.0f);
}

// One LSTM step for this thread's quarter of the hidden state.
template <int Q16>
__device__ __forceinline__ void lstm_quarter(
    const float e[32], const float hf[64], float cq[16],
    const float* __restrict__ Wih, const float* __restrict__ Whh,
    const float* __restrict__ bias, int q, float* __restrict__ h_row)
{
#pragma unroll
    for (int jj = 0; jj < 16; ++jj) {
        const int j = q * 16 + jj;
        float ai = bias[j];
        float af = bias[64 + j];
        float ag = bias[128 + j];
        float ao = bias[192 + j];
#pragma unroll
        for (int k = 0; k < 32; ++k) {
            const float xv = e[k];
            ai = fmaf(Wih[j * 32 + k],         xv, ai);
            af = fmaf(Wih[(64 + j) * 32 + k],  xv, af);
            ag = fmaf(Wih[(128 + j) * 32 + k], xv, ag);
            ao = fmaf(Wih[(192 + j) * 32 + k], xv, ao);
        }
#pragma unroll
        for (int k = 0; k < 64; ++k) {
            const float hv = hf[k];
            ai = fmaf(Whh[j * 64 + k],         hv, ai);
            af = fmaf(Whh[(64 + j) * 64 + k],  hv, af);
            ag = fmaf(Whh[(128 + j) * 64 + k], hv, ag);
            ao = fmaf(Whh[(192 + j) * 64 + k], hv, ao);
        }
        const float iv = sigm(ai);
        const float fv = sigm(af);
        const float gv = tanh_f(ag);
        const float ov = sigm(ao);
        const float cn = fmaf(fv, cq[jj], iv * gv);
        cq[jj] = cn;
        h_row[j] = ov * tanh_f(cn);
    }
}

// amdgpu_waves_per_eu(2,2): pin regalloc to exactly 2 waves/EU -> 256-VGPR
// budget. launch_bounds(256,2) alone only sets the MIN (cap), and the
// backend's occupancy heuristic still targeted 4 waves/EU -> 128 VGPR ->
// catastrophic scratch spill (R2: FETCH 157 GB, 75 ms).
extern "C" __global__ void
__launch_bounds__(256)
__attribute__((amdgpu_waves_per_eu(2, 2)))
traj_fused(const float* __restrict__ obs,
           const float* __restrict__ noise,
           const float* __restrict__ scene,
           const float* __restrict__ W_emb,  const float* __restrict__ b_emb,
           const float* __restrict__ Wih_e,  const float* __restrict__ Whh_e, const float* __restrict__ b_e,
           const float* __restrict__ W_h,    const float* __restrict__ b_h,
           const float* __restrict__ W_c,    const float* __restrict__ b_c,
           const float* __restrict__ Wih_d,  const float* __restrict__ Whh_d, const float* __restrict__ b_d,
           const float* __restrict__ W_out,  const float* __restrict__ b_out,
           float* __restrict__ out)
{
    // 256 threads = 4 waves. lane l = batch element (local), wave q = hidden quarter.
    __shared__ float h_lds[2][64][65];   // stride 65: bank=(l+k)%32 -> 2-way (free)

    const int l = threadIdx.x & 63;
    const int q = threadIdx.x >> 6;
    const int b = blockIdx.x * 64 + l;

    const float* ob = obs + (size_t)b * (OBS_LEN * 2);

    float hf[64];
    float cq[16];
#pragma unroll
    for (int k = 0; k < 64; ++k) hf[k] = 0.0f;
#pragma unroll
    for (int k = 0; k < 16; ++k) cq[k] = 0.0f;

    int buf = 0;

    // ---------------- encoder ----------------
#pragma unroll 1
    for (int t = 0; t < OBS_LEN; ++t) {
        const float x0 = ob[2 * t + 0];
        const float x1 = ob[2 * t + 1];
        float e[32];
#pragma unroll
        for (int k = 0; k < 32; ++k)
            e[k] = fmaxf(0.0f, fmaf(W_emb[2 * k], x0,
                                fmaf(W_emb[2 * k + 1], x1, b_emb[k])));

        lstm_quarter<0>(e, hf, cq, Wih_e, Whh_e, b_e, q, &h_lds[buf][l][0]);
        __syncthreads();
#pragma unroll
        for (int k = 0; k < 64; ++k) hf[k] = h_lds[buf][l][k];
        buf ^= 1;
    }

    // ---------------- cond -> decoder init state ----------------
    {
        float ah[16], ac[16];
#pragma unroll
        for (int jj = 0; jj < 16; ++jj) {
            ah[jj] = b_h[q * 16 + jj];
            ac[jj] = b_c[q * 16 + jj];
        }
#pragma unroll
        for (int k = 0; k < 64; ++k) {          // h_last part
            const float hv = hf[k];
#pragma unroll
            for (int jj = 0; jj < 16; ++jj) {
                ah[jj] = fmaf(W_h[(q * 16 + jj) * 144 + k], hv, ah[jj]);
                ac[jj] = fmaf(W_c[(q * 16 + jj) * 144 + k], hv, ac[jj]);
            }
        }
        const float* np_ = noise + (size_t)b * 16;
#pragma unroll 4
        for (int k = 0; k < 16; ++k) {          // noise part
            const float nv = np_[k];
#pragma unroll
            for (int jj = 0; jj < 16; ++jj) {
                ah[jj] = fmaf(W_h[(q * 16 + jj) * 144 + 64 + k], nv, ah[jj]);
                ac[jj] = fmaf(W_c[(q * 16 + jj) * 144 + 64 + k], nv, ac[jj]);
            }
        }
        const float* sp = scene + (size_t)b * 64;
#pragma unroll 4
        for (int k = 0; k < 64; ++k) {          // scene part
            const float sv = sp[k];
#pragma unroll
            for (int jj = 0; jj < 16; ++jj) {
                ah[jj] = fmaf(W_h[(q * 16 + jj) * 144 + 80 + k], sv, ah[jj]);
                ac[jj] = fmaf(W_c[(q * 16 + jj) * 144 + 80 + k], sv, ac[jj]);
            }
        }
#pragma unroll
        for (int jj = 0; jj < 16; ++jj) {
            h_lds[buf][l][q * 16 + jj] = ah[jj];
            cq[jj] = ac[jj];
        }
        __syncthreads();
#pragma unroll
        for (int k = 0; k < 64; ++k) hf[k] = h_lds[buf][l][k];
        buf ^= 1;
    }

    // ---------------- autoregressive decoder ----------------
    float x0 = ob[2 * (OBS_LEN - 1) + 0];
    float x1 = ob[2 * (OBS_LEN - 1) + 1];
    float* op = out + (size_t)b * (PRED_LEN * 2);

#pragma unroll 1
    for (int t = 0; t < PRED_LEN; ++t) {
        float e[32];
#pragma unroll
        for (int k = 0; k < 32; ++k)
            e[k] = fmaxf(0.0f, fmaf(W_emb[2 * k], x0,
                                fmaf(W_emb[2 * k + 1], x1, b_emb[k])));

        lstm_quarter<1>(e, hf, cq, Wih_d, Whh_d, b_d, q, &h_lds[buf][l][0]);
        __syncthreads();
#pragma unroll
        for (int k = 0; k < 64; ++k) hf[k] = h_lds[buf][l][k];
        buf ^= 1;

        // output head: all threads compute redundantly (keeps x0/x1 local, no sync)
        float y0 = b_out[0];
        float y1 = b_out[1];
#pragma unroll
        for (int j = 0; j < 64; ++j) {
            y0 = fmaf(W_out[j],      hf[j], y0);
            y1 = fmaf(W_out[64 + j], hf[j], y1);
        }
        if (q == 0) {                    // wave-uniform branch
            op[2 * t + 0] = y0;
            op[2 * t + 1] = y1;
        }
        x0 = y0;
        x1 = y1;
    }
}

extern "C" void kernel_launch(void* const* d_in, const int* in_sizes, int n_in,
                              void* d_out, int out_size, void* d_ws, size_t ws_size,
                              hipStream_t stream) {
    (void)in_sizes; (void)n_in; (void)d_ws; (void)ws_size; (void)out_size;
    const float* obs    = (const float*)d_in[0];
    const float* noise  = (const float*)d_in[1];
    const float* scene  = (const float*)d_in[2];
    const float* W_emb  = (const float*)d_in[3];
    const float* b_emb  = (const float*)d_in[4];
    const float* Wih_e  = (const float*)d_in[5];
    const float* Whh_e  = (const float*)d_in[6];
    const float* b_e    = (const float*)d_in[7];
    const float* W_h    = (const float*)d_in[8];
    const float* b_h    = (const float*)d_in[9];
    const float* W_c    = (const float*)d_in[10];
    const float* b_c    = (const float*)d_in[11];
    const float* Wih_d  = (const float*)d_in[12];
    const float* Whh_d  = (const float*)d_in[13];
    const float* b_d    = (const float*)d_in[14];
    const float* W_out  = (const float*)d_in[15];
    const float* b_out  = (const float*)d_in[16];
    float* out = (float*)d_out;

    dim3 grid(B_TOTAL / 64), block(256);
    hipLaunchKernelGGL(traj_fused, grid, block, 0, stream,
                       obs, noise, scene, W_emb, b_emb,
                       Wih_e, Whh_e, b_e, W_h, b_h, W_c, b_c,
                       Wih_d, Whh_d, b_d, W_out, b_out, out);
}

// Round 4
// 5684.020 us; speedup vs baseline: 13.2213x; 13.2203x over previous
//
#include <hip/hip_runtime.h>
#include <cstddef>

#define B_TOTAL  65536
#define OBS_LEN  20
#define PRED_LEN 30
#define HSTR     68   // h row stride in floats: 272B rows, 16B-aligned, capacity-even b128

__device__ __forceinline__ float sigm(float x) {
    return __builtin_amdgcn_rcpf(1.0f + __expf(-x));
}
__device__ __forceinline__ float tanh_f(float x) {
    return fmaf(2.0f, sigm(2.0f * x), -1.0f);
}

// One LSTM step for this thread's 16 hidden units, h streamed from LDS.
// Live registers bounded: 4x8 accums + e[32] + cq[16] + h4 ≈ 105 -> no spill at 128.
__device__ __forceinline__ void lstm_step(
    const float e[32], const float* hin, float cq[16],
    const float* __restrict__ Wih, const float* __restrict__ Whh,
    const float* __restrict__ bias, int q, float* hout)
{
#pragma unroll
    for (int half = 0; half < 2; ++half) {
        float a0[8], a1[8], a2[8], a3[8];
#pragma unroll
        for (int jj = 0; jj < 8; ++jj) {
            const int j = q * 16 + half * 8 + jj;
            a0[jj] = bias[j];
            a1[jj] = bias[64 + j];
            a2[jj] = bias[128 + j];
            a3[jj] = bias[192 + j];
        }
        // x @ Wih^T : e in registers, weights via wave-uniform s_load
#pragma unroll
        for (int k = 0; k < 32; ++k) {
            const float xv = e[k];
#pragma unroll
            for (int jj = 0; jj < 8; ++jj) {
                const int j = q * 16 + half * 8 + jj;
                a0[jj] = fmaf(Wih[j * 32 + k],         xv, a0[jj]);
                a1[jj] = fmaf(Wih[(64 + j) * 32 + k],  xv, a1[jj]);
                a2[jj] = fmaf(Wih[(128 + j) * 32 + k], xv, a2[jj]);
                a3[jj] = fmaf(Wih[(192 + j) * 32 + k], xv, a3[jj]);
            }
        }
        // h @ Whh^T : h streamed from LDS as float4
#pragma unroll
        for (int kc = 0; kc < 16; ++kc) {
            const float4 h4 = *(const float4*)(hin + kc * 4);
            const float hv[4] = {h4.x, h4.y, h4.z, h4.w};
#pragma unroll
            for (int kk = 0; kk < 4; ++kk) {
                const int k = kc * 4 + kk;
#pragma unroll
                for (int jj = 0; jj < 8; ++jj) {
                    const int j = q * 16 + half * 8 + jj;
                    a0[jj] = fmaf(Whh[j * 64 + k],         hv[kk], a0[jj]);
                    a1[jj] = fmaf(Whh[(64 + j) * 64 + k],  hv[kk], a1[jj]);
                    a2[jj] = fmaf(Whh[(128 + j) * 64 + k], hv[kk], a2[jj]);
                    a3[jj] = fmaf(Whh[(192 + j) * 64 + k], hv[kk], a3[jj]);
                }
            }
        }
#pragma unroll
        for (int jj = 0; jj < 8; ++jj) {
            const int jq = half * 8 + jj;
            const float iv = sigm(a0[jj]);
            const float fv = sigm(a1[jj]);
            const float gv = tanh_f(a2[jj]);
            const float ov = sigm(a3[jj]);
            const float cn = fmaf(fv, cq[jq], iv * gv);
            cq[jq] = cn;
            hout[q * 16 + jq] = ov * tanh_f(cn);
        }
    }
}

extern "C" __global__ void __launch_bounds__(256)
traj_fused(const float* __restrict__ obs,
           const float* __restrict__ noise,
           const float* __restrict__ scene,
           const float* __restrict__ W_emb,  const float* __restrict__ b_emb,
           const float* __restrict__ Wih_e,  const float* __restrict__ Whh_e, const float* __restrict__ b_e,
           const float* __restrict__ W_h,    const float* __restrict__ b_h,
           const float* __restrict__ W_c,    const float* __restrict__ b_c,
           const float* __restrict__ Wih_d,  const float* __restrict__ Whh_d, const float* __restrict__ b_d,
           const float* __restrict__ W_out,  const float* __restrict__ b_out,
           float* __restrict__ out)
{
    __shared__ float h_lds[2][64][HSTR];

    const int l = threadIdx.x & 63;
    // readfirstlane: provably wave-uniform -> weight addresses become scalar (s_load)
    const int q = __builtin_amdgcn_readfirstlane((int)(threadIdx.x >> 6));
    const int b = blockIdx.x * 64 + l;

    const float* ob = obs + (size_t)b * (OBS_LEN * 2);

    float cq[16];
#pragma unroll
    for (int k = 0; k < 16; ++k) cq[k] = 0.0f;
#pragma unroll
    for (int jj = 0; jj < 16; ++jj) h_lds[0][l][q * 16 + jj] = 0.0f;
    __syncthreads();

    int buf = 0;

    // ---------------- encoder ----------------
#pragma unroll 1
    for (int t = 0; t < OBS_LEN; ++t) {
        const float x0 = ob[2 * t + 0];
        const float x1 = ob[2 * t + 1];
        float e[32];
#pragma unroll
        for (int k = 0; k < 32; ++k)
            e[k] = fmaxf(0.0f, fmaf(W_emb[2 * k], x0,
                                fmaf(W_emb[2 * k + 1], x1, b_emb[k])));
        lstm_step(e, &h_lds[buf][l][0], cq, Wih_e, Whh_e, b_e, q,
                  &h_lds[buf ^ 1][l][0]);
        __syncthreads();
        buf ^= 1;
    }

    // ---------------- cond -> decoder init state ----------------
    {
        const float* hin = &h_lds[buf][l][0];
        const float4* np4 = (const float4*)(noise + (size_t)b * 16);
        const float4* sp4 = (const float4*)(scene + (size_t)b * 64);
#pragma unroll
        for (int half = 0; half < 2; ++half) {
            float ah[8], ac[8];
#pragma unroll
            for (int jj = 0; jj < 8; ++jj) {
                const int j = q * 16 + half * 8 + jj;
                ah[jj] = b_h[j];
                ac[jj] = b_c[j];
            }
            // h_last part (k 0..63) from LDS
#pragma unroll
            for (int kc = 0; kc < 16; ++kc) {
                const float4 h4 = *(const float4*)(hin + kc * 4);
                const float hv[4] = {h4.x, h4.y, h4.z, h4.w};
#pragma unroll
                for (int kk = 0; kk < 4; ++kk) {
                    const int k = kc * 4 + kk;
#pragma unroll
                    for (int jj = 0; jj < 8; ++jj) {
                        const int j = q * 16 + half * 8 + jj;
                        ah[jj] = fmaf(W_h[j * 144 + k], hv[kk], ah[jj]);
                        ac[jj] = fmaf(W_c[j * 144 + k], hv[kk], ac[jj]);
                    }
                }
            }
            // noise part (k 64..79)
#pragma unroll
            for (int kc = 0; kc < 4; ++kc) {
                const float4 n4 = np4[kc];
                const float nv[4] = {n4.x, n4.y, n4.z, n4.w};
#pragma unroll
                for (int kk = 0; kk < 4; ++kk) {
                    const int k = 64 + kc * 4 + kk;
#pragma unroll
                    for (int jj = 0; jj < 8; ++jj) {
                        const int j = q * 16 + half * 8 + jj;
                        ah[jj] = fmaf(W_h[j * 144 + k], nv[kk], ah[jj]);
                        ac[jj] = fmaf(W_c[j * 144 + k], nv[kk], ac[jj]);
                    }
                }
            }
            // scene part (k 80..143)
#pragma unroll
            for (int kc = 0; kc < 16; ++kc) {
                const float4 s4 = sp4[kc];
                const float sv[4] = {s4.x, s4.y, s4.z, s4.w};
#pragma unroll
                for (int kk = 0; kk < 4; ++kk) {
                    const int k = 80 + kc * 4 + kk;
#pragma unroll
                    for (int jj = 0; jj < 8; ++jj) {
                        const int j = q * 16 + half * 8 + jj;
                        ah[jj] = fmaf(W_h[j * 144 + k], sv[kk], ah[jj]);
                        ac[jj] = fmaf(W_c[j * 144 + k], sv[kk], ac[jj]);
                    }
                }
            }
#pragma unroll
            for (int jj = 0; jj < 8; ++jj) {
                h_lds[buf ^ 1][l][q * 16 + half * 8 + jj] = ah[jj];
                cq[half * 8 + jj] = ac[jj];
            }
        }
        __syncthreads();
        buf ^= 1;
    }

    // ---------------- autoregressive decoder ----------------
    float x0 = ob[2 * (OBS_LEN - 1) + 0];
    float x1 = ob[2 * (OBS_LEN - 1) + 1];
    float* op = out + (size_t)b * (PRED_LEN * 2);

#pragma unroll 1
    for (int t = 0; t < PRED_LEN; ++t) {
        float e[32];
#pragma unroll
        for (int k = 0; k < 32; ++k)
            e[k] = fmaxf(0.0f, fmaf(W_emb[2 * k], x0,
                                fmaf(W_emb[2 * k + 1], x1, b_emb[k])));
        lstm_step(e, &h_lds[buf][l][0], cq, Wih_d, Whh_d, b_d, q,
                  &h_lds[buf ^ 1][l][0]);
        __syncthreads();
        buf ^= 1;

        // output head: all waves compute redundantly (keeps x local, no extra sync)
        float y0 = b_out[0];
        float y1 = b_out[1];
#pragma unroll
        for (int kc = 0; kc < 16; ++kc) {
            const float4 h4 = *(const float4*)(&h_lds[buf][l][kc * 4]);
            const float hv[4] = {h4.x, h4.y, h4.z, h4.w};
#pragma unroll
            for (int kk = 0; kk < 4; ++kk) {
                const int j = kc * 4 + kk;
                y0 = fmaf(W_out[j],      hv[kk], y0);
                y1 = fmaf(W_out[64 + j], hv[kk], y1);
            }
        }
        if (q == 0) {
            op[2 * t + 0] = y0;
            op[2 * t + 1] = y1;
        }
        x0 = y0;
        x1 = y1;
    }
}

extern "C" void kernel_launch(void* const* d_in, const int* in_sizes, int n_in,
                              void* d_out, int out_size, void* d_ws, size_t ws_size,
                              hipStream_t stream) {
    (void)in_sizes; (void)n_in; (void)d_ws; (void)ws_size; (void)out_size;
    const float* obs    = (const float*)d_in[0];
    const float* noise  = (const float*)d_in[1];
    const float* scene  = (const float*)d_in[2];
    const float* W_emb  = (const float*)d_in[3];
    const float* b_emb  = (const float*)d_in[4];
    const float* Wih_e  = (const float*)d_in[5];
    const float* Whh_e  = (const float*)d_in[6];
    const float* b_e    = (const float*)d_in[7];
    const float* W_h    = (const float*)d_in[8];
    const float* b_h    = (const float*)d_in[9];
    const float* W_c    = (const float*)d_in[10];
    const float* b_c    = (const float*)d_in[11];
    const float* Wih_d  = (const float*)d_in[12];
    const float* Whh_d  = (const float*)d_in[13];
    const float* b_d    = (const float*)d_in[14];
    const float* W_out  = (const float*)d_in[15];
    const float* b_out  = (const float*)d_in[16];
    float* out = (float*)d_out;

    dim3 grid(B_TOTAL / 64), block(256);
    hipLaunchKernelGGL(traj_fused, grid, block, 0, stream,
                       obs, noise, scene, W_emb, b_emb,
                       Wih_e, Whh_e, b_e, W_h, b_h, W_c, b_c,
                       Wih_d, Whh_d, b_d, W_out, b_out, out);
}

// Round 5
// 588.848 us; speedup vs baseline: 127.6223x; 9.6528x over previous
//
#include <hip/hip_runtime.h>
#include <hip/hip_bf16.h>
#include <cstddef>

#define OBS_LEN  20
#define PRED_LEN 30

typedef __attribute__((ext_vector_type(8))) short short8v;  // 8 bf16 (4 VGPRs)
typedef __attribute__((ext_vector_type(4))) float f32x4;

__device__ __forceinline__ float sigm(float x) {
    return __builtin_amdgcn_rcpf(1.0f + __expf(-x));
}
__device__ __forceinline__ float tanh_f(float x) {
    return fmaf(2.0f, sigm(2.0f * x), -1.0f);
}
__device__ __forceinline__ unsigned short f2bf(float x) {  // RNE
    __hip_bfloat16 h = __float2bfloat16(x);
    return __builtin_bit_cast(unsigned short, h);
}
__device__ __forceinline__ float bf2f(unsigned short u) {
    unsigned v = ((unsigned)u) << 16;
    return __builtin_bit_cast(float, v);
}
// load 8 consecutive f32 from a weight row, convert to bf16x8 fragment
__device__ __forceinline__ short8v ldw8(const float* __restrict__ p) {
    const float4 a = *(const float4*)(p);
    const float4 b = *(const float4*)(p + 4);
    short8v r;
    r[0] = (short)f2bf(a.x); r[1] = (short)f2bf(a.y);
    r[2] = (short)f2bf(a.z); r[3] = (short)f2bf(a.w);
    r[4] = (short)f2bf(b.x); r[5] = (short)f2bf(b.y);
    r[6] = (short)f2bf(b.z); r[7] = (short)f2bf(b.w);
    return r;
}

#define MFMA(A, B, C) __builtin_amdgcn_mfma_f32_16x16x32_bf16((A), (B), (C), 0, 0, 0)

// Block: 256 threads = 4 waves, 16 batch rows.
// Wave w owns gate columns t*64 + w*16 + (lane&15) for gate types t=0..3
// -> each lane holds i,f,g,o for the SAME (batch,j): elementwise is in-register.
// Weights stay in VGPRs as B-fragments for the whole kernel (loaded once).
// h recurrence: bf16 hi + lo residual through LDS (lo pass reuses Whh frags).
// LDS padded to ~55KB: forces 2 blocks/CU -> regalloc targets 2 waves/EU ->
// 256-VGPR budget -> no spill (R2/R3 lesson: heuristic targeted 4 -> spilled).
extern "C" __global__ void __launch_bounds__(256, 2)
traj_mfma(const float* __restrict__ obs,   const float* __restrict__ noise,
          const float* __restrict__ scene,
          const float* __restrict__ W_emb, const float* __restrict__ b_emb,
          const float* __restrict__ Wih_e, const float* __restrict__ Whh_e, const float* __restrict__ b_e,
          const float* __restrict__ W_h,   const float* __restrict__ b_h,
          const float* __restrict__ W_c,   const float* __restrict__ b_c,
          const float* __restrict__ Wih_d, const float* __restrict__ Whh_d, const float* __restrict__ b_d,
          const float* __restrict__ W_out, const float* __restrict__ b_out,
          float* __restrict__ out)
{
    __shared__ __align__(16) unsigned short hbuf[2][2][16 * 72]; // [buf][hi/lo], row stride 72 bf16
    __shared__ __align__(16) unsigned short e_l[16 * 40];        // e tile, stride 40 bf16
    __shared__ __align__(16) unsigned short ns_l[16 * 96];       // [noise16|scene64|zero16]
    __shared__ __align__(16) float obs_l[640];                   // 16 rows x 40 f32
    __shared__ __align__(16) float y_part[16 * 8];               // [i][w*2+c]
    __shared__ float occ_pad[9600];                              // occupancy clamp -> 2 blocks/CU

    const int id = threadIdx.x;
    // keep occ_pad alive (never executes: grid is 4096 blocks)
    if (blockIdx.x == 0xFFFFFFFFu) { occ_pad[id] = 1.0f; out[id] = occ_pad[id ^ 1]; }

    const int l    = id & 63;
    const int w    = id >> 6;        // wave = n-tile slot
    const int q    = l >> 4;
    const int jm   = l & 15;
    const int colb = w * 16 + jm;    // j in [0,64)
    const int bb   = blockIdx.x * 16;

    // ---------------- one-time register-resident weights ----------------
    short8v Be[3][4], Bd[3][4];
    float bias_e[4], bias_d[4];
#pragma unroll
    for (int t = 0; t < 4; ++t) {
        const int row = t * 64 + colb;                 // PyTorch gate row
        Be[0][t] = ldw8(Wih_e + row * 32 + 8 * q);     // k 0..31  (e)
        Be[1][t] = ldw8(Whh_e + row * 64 + 8 * q);     // k 32..63 (h lo half)
        Be[2][t] = ldw8(Whh_e + row * 64 + 32 + 8 * q);// k 64..95 (h hi half)
        Bd[0][t] = ldw8(Wih_d + row * 32 + 8 * q);
        Bd[1][t] = ldw8(Whh_d + row * 64 + 8 * q);
        Bd[2][t] = ldw8(Whh_d + row * 64 + 32 + 8 * q);
        bias_e[t] = b_e[row];
        bias_d[t] = b_d[row];
    }
    const int i_e = id >> 4;          // embed: batch row
    const int u_e = (id & 15) * 2;    // embed: unit pair
    const float4 we  = *(const float4*)(W_emb + u_e * 2);
    const float be0 = b_emb[u_e], be1 = b_emb[u_e + 1];
    const float wo0 = W_out[colb], wo1 = W_out[64 + colb];
    const float bo0 = b_out[0],   bo1 = b_out[1];

    // init h=0, stage obs
    {
        unsigned* hz = (unsigned*)&hbuf[0][0][0];
        for (int k2 = id; k2 < 1152; k2 += 256) hz[k2] = 0u;   // hi+lo of buf0
        for (int k2 = id; k2 < 640; k2 += 256) obs_l[k2] = obs[(size_t)bb * 40 + k2];
    }
    float c[4] = {0.f, 0.f, 0.f, 0.f};
    __syncthreads();

    int cur = 0;

    // ==================== encoder ====================
#pragma unroll 1
    for (int t = 0; t < OBS_LEN; ++t) {
        {   // embed: e = relu(x @ W_emb^T + b)
            const float x0 = obs_l[i_e * 40 + 2 * t];
            const float x1 = obs_l[i_e * 40 + 2 * t + 1];
            const float e0 = fmaxf(0.f, fmaf(we.x, x0, fmaf(we.y, x1, be0)));
            const float e1 = fmaxf(0.f, fmaf(we.z, x0, fmaf(we.w, x1, be1)));
            ((unsigned*)e_l)[i_e * 20 + (u_e >> 1)] =
                (unsigned)f2bf(e0) | ((unsigned)f2bf(e1) << 16);
        }
        __syncthreads();

        const unsigned short* hh = &hbuf[cur][0][0];
        const unsigned short* hl = &hbuf[cur][1][0];
        const short8v Ae = *(const short8v*)(e_l + jm * 40 + 8 * q);
        const short8v H1 = *(const short8v*)(hh + jm * 72 + 8 * q);
        const short8v H2 = *(const short8v*)(hh + jm * 72 + 32 + 8 * q);
        const short8v L1 = *(const short8v*)(hl + jm * 72 + 8 * q);
        const short8v L2 = *(const short8v*)(hl + jm * 72 + 32 + 8 * q);
        unsigned short* nh = &hbuf[cur ^ 1][0][0];
        unsigned short* nl = &hbuf[cur ^ 1][1][0];

        f32x4 gacc[4];
#pragma unroll
        for (int t4 = 0; t4 < 4; ++t4) {
            f32x4 acc = {bias_e[t4], bias_e[t4], bias_e[t4], bias_e[t4]};
            acc = MFMA(Ae, Be[0][t4], acc);
            acc = MFMA(H1, Be[1][t4], acc);
            acc = MFMA(H2, Be[2][t4], acc);
            acc = MFMA(L1, Be[1][t4], acc);   // lo-residual pass, same Whh frags
            acc = MFMA(L2, Be[2][t4], acc);
            gacc[t4] = acc;
        }
#pragma unroll
        for (int r = 0; r < 4; ++r) {
            const float ig = sigm(gacc[0][r]);
            const float fg = sigm(gacc[1][r]);
            const float gg = tanh_f(gacc[2][r]);
            const float og = sigm(gacc[3][r]);
            c[r] = fmaf(fg, c[r], ig * gg);
            const float hv = og * tanh_f(c[r]);
            const unsigned short hb = f2bf(hv);
            nh[(4 * q + r) * 72 + colb] = hb;
            nl[(4 * q + r) * 72 + colb] = f2bf(hv - bf2f(hb));
        }
        cur ^= 1;
        __syncthreads();
    }

    // ==================== cond -> decoder init ====================
    {
        {   // stage [noise | scene | 0] as bf16
            const int i2 = id >> 4, cb = (id & 15) * 6;
#pragma unroll
            for (int cc = 0; cc < 6; ++cc) {
                const int col = cb + cc;
                float v;
                if (col < 16)      v = noise[(size_t)(bb + i2) * 16 + col];
                else if (col < 80) v = scene[(size_t)(bb + i2) * 64 + (col - 16)];
                else               v = 0.f;
                ns_l[i2 * 96 + col] = f2bf(v);
            }
        }
        __syncthreads();

        const unsigned short* hh = &hbuf[cur][0][0];
        const unsigned short* hl = &hbuf[cur][1][0];
        const short8v A0 = *(const short8v*)(hh + jm * 72 + 8 * q);
        const short8v A1 = *(const short8v*)(hh + jm * 72 + 32 + 8 * q);
        const short8v L0 = *(const short8v*)(hl + jm * 72 + 8 * q);
        const short8v L1c = *(const short8v*)(hl + jm * 72 + 32 + 8 * q);
        const short8v N0 = *(const short8v*)(ns_l + jm * 96 + 8 * q);
        const short8v N1 = *(const short8v*)(ns_l + jm * 96 + 32 + 8 * q);
        const short8v N2 = *(const short8v*)(ns_l + jm * 96 + 64 + 8 * q);
        unsigned short* nh = &hbuf[cur ^ 1][0][0];
        unsigned short* nl = &hbuf[cur ^ 1][1][0];
        const short8v zfrag = {0, 0, 0, 0, 0, 0, 0, 0};

        // ---- h0 = cond @ W_h^T + b_h ----  (wave w computes n-tile w: j = colb)
        {
            short8v Bf[5];
#pragma unroll
            for (int kt = 0; kt < 4; ++kt)
                Bf[kt] = ldw8(W_h + (size_t)colb * 144 + kt * 32 + 8 * q);
            Bf[4] = (q < 2) ? ldw8(W_h + (size_t)colb * 144 + 128 + 8 * q) : zfrag;
            f32x4 ah = {b_h[colb], b_h[colb], b_h[colb], b_h[colb]};
            ah = MFMA(A0, Bf[0], ah);
            ah = MFMA(A1, Bf[1], ah);
            ah = MFMA(L0, Bf[0], ah);
            ah = MFMA(L1c, Bf[1], ah);
            ah = MFMA(N0, Bf[2], ah);
            ah = MFMA(N1, Bf[3], ah);
            ah = MFMA(N2, Bf[4], ah);
#pragma unroll
            for (int r = 0; r < 4; ++r) {
                const float hv = ah[r];
                const unsigned short hb = f2bf(hv);
                nh[(4 * q + r) * 72 + colb] = hb;
                nl[(4 * q + r) * 72 + colb] = f2bf(hv - bf2f(hb));
            }
        }
        // ---- c0 = cond @ W_c^T + b_c ----
        {
            short8v Bf[5];
#pragma unroll
            for (int kt = 0; kt < 4; ++kt)
                Bf[kt] = ldw8(W_c + (size_t)colb * 144 + kt * 32 + 8 * q);
            Bf[4] = (q < 2) ? ldw8(W_c + (size_t)colb * 144 + 128 + 8 * q) : zfrag;
            f32x4 ac = {b_c[colb], b_c[colb], b_c[colb], b_c[colb]};
            ac = MFMA(A0, Bf[0], ac);
            ac = MFMA(A1, Bf[1], ac);
            ac = MFMA(L0, Bf[0], ac);
            ac = MFMA(L1c, Bf[1], ac);
            ac = MFMA(N0, Bf[2], ac);
            ac = MFMA(N1, Bf[3], ac);
            ac = MFMA(N2, Bf[4], ac);
#pragma unroll
            for (int r = 0; r < 4; ++r) c[r] = ac[r];
        }
        cur ^= 1;
        __syncthreads();
    }

    // ==================== decoder ====================
#pragma unroll 1
    for (int t = 0; t < PRED_LEN; ++t) {
        {   // embed from y_{t-1} (or obs[:, -1] at t=0); also store y_{t-1}
            float x0, x1;
            if (t == 0) {
                x0 = obs_l[i_e * 40 + 38];
                x1 = obs_l[i_e * 40 + 39];
            } else {
                const float* yp = y_part + i_e * 8;
                x0 = yp[0] + yp[2] + yp[4] + yp[6] + bo0;
                x1 = yp[1] + yp[3] + yp[5] + yp[7] + bo1;
                if ((id & 15) == 0)
                    *(float2*)(out + (size_t)(bb + i_e) * 60 + (t - 1) * 2) =
                        make_float2(x0, x1);
            }
            const float e0 = fmaxf(0.f, fmaf(we.x, x0, fmaf(we.y, x1, be0)));
            const float e1 = fmaxf(0.f, fmaf(we.z, x0, fmaf(we.w, x1, be1)));
            ((unsigned*)e_l)[i_e * 20 + (u_e >> 1)] =
                (unsigned)f2bf(e0) | ((unsigned)f2bf(e1) << 16);
        }
        __syncthreads();

        const unsigned short* hh = &hbuf[cur][0][0];
        const unsigned short* hl = &hbuf[cur][1][0];
        const short8v Ae = *(const short8v*)(e_l + jm * 40 + 8 * q);
        const short8v H1 = *(const short8v*)(hh + jm * 72 + 8 * q);
        const short8v H2 = *(const short8v*)(hh + jm * 72 + 32 + 8 * q);
        const short8v L1 = *(const short8v*)(hl + jm * 72 + 8 * q);
        const short8v L2 = *(const short8v*)(hl + jm * 72 + 32 + 8 * q);
        unsigned short* nh = &hbuf[cur ^ 1][0][0];
        unsigned short* nl = &hbuf[cur ^ 1][1][0];

        f32x4 gacc[4];
#pragma unroll
        for (int t4 = 0; t4 < 4; ++t4) {
            f32x4 acc = {bias_d[t4], bias_d[t4], bias_d[t4], bias_d[t4]};
            acc = MFMA(Ae, Bd[0][t4], acc);
            acc = MFMA(H1, Bd[1][t4], acc);
            acc = MFMA(H2, Bd[2][t4], acc);
            acc = MFMA(L1, Bd[1][t4], acc);
            acc = MFMA(L2, Bd[2][t4], acc);
            gacc[t4] = acc;
        }
        float hr[4];
#pragma unroll
        for (int r = 0; r < 4; ++r) {
            const float ig = sigm(gacc[0][r]);
            const float fg = sigm(gacc[1][r]);
            const float gg = tanh_f(gacc[2][r]);
            const float og = sigm(gacc[3][r]);
            c[r] = fmaf(fg, c[r], ig * gg);
            const float hv = og * tanh_f(c[r]);
            hr[r] = hv;
            const unsigned short hb = f2bf(hv);
            nh[(4 * q + r) * 72 + colb] = hb;
            nl[(4 * q + r) * 72 + colb] = f2bf(hv - bf2f(hb));
        }
        // y partials: reduce over this wave's 16 j's (butterfly in low 4 lane bits)
        float p0[4], p1[4];
#pragma unroll
        for (int r = 0; r < 4; ++r) { p0[r] = hr[r] * wo0; p1[r] = hr[r] * wo1; }
#pragma unroll
        for (int m = 1; m < 16; m <<= 1) {
#pragma unroll
            for (int r = 0; r < 4; ++r) {
                p0[r] += __shfl_xor(p0[r], m, 64);
                p1[r] += __shfl_xor(p1[r], m, 64);
            }
        }
        if (jm < 2) {
#pragma unroll
            for (int r = 0; r < 4; ++r)
                y_part[(4 * q + r) * 8 + w * 2 + jm] = (jm == 0) ? p0[r] : p1[r];
        }
        cur ^= 1;
        __syncthreads();
    }

    // final y (t = PRED_LEN-1)
    if ((id & 15) == 0) {
        const float* yp = y_part + i_e * 8;
        const float x0 = yp[0] + yp[2] + yp[4] + yp[6] + bo0;
        const float x1 = yp[1] + yp[3] + yp[5] + yp[7] + bo1;
        *(float2*)(out + (size_t)(bb + i_e) * 60 + (PRED_LEN - 1) * 2) =
            make_float2(x0, x1);
    }
}

extern "C" void kernel_launch(void* const* d_in, const int* in_sizes, int n_in,
                              void* d_out, int out_size, void* d_ws, size_t ws_size,
                              hipStream_t stream) {
    (void)in_sizes; (void)n_in; (void)d_ws; (void)ws_size; (void)out_size;
    const float* obs    = (const float*)d_in[0];
    const float* noise  = (const float*)d_in[1];
    const float* scene  = (const float*)d_in[2];
    const float* W_emb  = (const float*)d_in[3];
    const float* b_emb  = (const float*)d_in[4];
    const float* Wih_e  = (const float*)d_in[5];
    const float* Whh_e  = (const float*)d_in[6];
    const float* b_e    = (const float*)d_in[7];
    const float* W_h    = (const float*)d_in[8];
    const float* b_h    = (const float*)d_in[9];
    const float* W_c    = (const float*)d_in[10];
    const float* b_c    = (const float*)d_in[11];
    const float* Wih_d  = (const float*)d_in[12];
    const float* Whh_d  = (const float*)d_in[13];
    const float* b_d    = (const float*)d_in[14];
    const float* W_out  = (const float*)d_in[15];
    const float* b_out  = (const float*)d_in[16];
    float* out = (float*)d_out;

    dim3 grid(65536 / 16), block(256);
    hipLaunchKernelGGL(traj_mfma, grid, block, 0, stream,
                       obs, noise, scene, W_emb, b_emb,
                       Wih_e, Whh_e, b_e, W_h, b_h, W_c, b_c,
                       Wih_d, Whh_d, b_d, W_out, b_out, out);
}